// Round 11
// baseline (190.482 us; speedup 1.0000x reference)
//
#include <hip/hip_runtime.h>
#include <hip/hip_bf16.h>
#include <hip/hip_cooperative_groups.h>

#define NB   32
#define TMEL 2048

typedef unsigned short u16;
typedef short s8v __attribute__((ext_vector_type(8)));
typedef float f4v __attribute__((ext_vector_type(4)));
typedef u16 u16x8 __attribute__((ext_vector_type(8)));

static __device__ __forceinline__ u16 f2bf(float v) {
    __hip_bfloat16 h = __float2bfloat16(v);
    return *(u16*)&h;
}

// ---------------------------------------------------------------------------
// Dispatch 1: gather + prep fused (no cross-block dependencies).
//  b in [0,1024):    gather role. batch n = b>>5, sub = b&31 -> rows
//                    [sub*64, sub*64+64) of batch n. Block re-scans its
//                    batch's target (redundant x32, ~1us) -> no idxv dep.
//  b in [1024,2176): Wt1 transpose.  b in [2176,2944): Wt2 transpose.
//  b==1024, tid<8:   zbuf zeroing.
// Wt[f][kc*DIN + d] = bf16(w[f][d][kc]);  w is [256][DIN][3]
// ---------------------------------------------------------------------------
__global__ __launch_bounds__(256) void gather_prep_kernel(
    const float* __restrict__ x,
    const int*   __restrict__ target,
    const float* __restrict__ w1,
    const float* __restrict__ w2,
    u16* __restrict__ Wt1,
    u16* __restrict__ Wt2,
    u16* __restrict__ zbuf,
    float* __restrict__ out0)
{
    __shared__ int c[512];
    __shared__ int ridx[64];
    const int b = blockIdx.x, tid = threadIdx.x;

    if (b >= 1024) {
        if (b == 1024 && tid < 8) {
            u16x8 z = {0, 0, 0, 0, 0, 0, 0, 0};
            *(u16x8*)(zbuf + tid * 8) = z;
        }
        if (b < 2176) {
            const int K = 1152, DIN = 384;
            int e = (b - 1024) * 256 + tid;
            int f = e / K;
            int rem = e - f * K;
            int kc = rem / DIN;
            int d = rem - kc * DIN;
            Wt1[e] = f2bf(w1[f * K + d * 3 + kc]);
        } else {
            const int K = 768, DIN = 256;
            int e = (b - 2176) * 256 + tid;
            int f = e / K;
            int rem = e - f * K;
            int kc = rem / DIN;
            int d = rem - kc * DIN;
            Wt2[e] = f2bf(w2[f * K + d * 3 + kc]);
        }
        return;
    }

    // ---- gather role ----
    const int n = b >> 5, sub = b & 31;
    c[tid]       = target[n * 512 + tid];
    c[tid + 256] = target[n * 512 + 256 + tid];
    __syncthreads();
    for (int off = 1; off < 512; off <<= 1) {
        int v0 = (tid       >= off) ? c[tid       - off] : 0;
        int v1 = (tid + 256 >= off) ? c[tid + 256 - off] : 0;
        __syncthreads();
        c[tid]       += v0;
        c[tid + 256] += v1;
        __syncthreads();
    }
    const int total = c[511];
    if (tid < 64) {
        int t = sub * 64 + tid;
        int lo = 0, hi = 512;
        while (lo < hi) {
            int mid = (lo + hi) >> 1;
            if (c[mid] <= t) lo = mid + 1; else hi = mid;
        }
        ridx[tid] = (t < total) ? min(lo, 511) : -1;
    }
    __syncthreads();

    // copy 64 rows x 96 f4 (2 slots per unit): 3072 units / 256 thr = 12
    const size_t xbase = (size_t)(n << 9) * 384;
    const size_t obase = ((size_t)(n << 11) + sub * 64) * 384;
    #pragma unroll 4
    for (int it = 0; it < 12; ++it) {
        int u  = tid + it * 256;
        int j  = u % 48;
        int rl = u / 48;
        int ie = ridx[rl];
        f4v v0 = {0.f, 0.f, 0.f, 0.f}, v1 = v0;
        if (ie >= 0) {
            const float* src = &x[xbase + (size_t)ie * 384];
            v0 = *(const f4v*)&src[j * 4];
            v1 = *(const f4v*)&src[(j + 48) * 4];
        }
        float* dst = &out0[obase + (size_t)rl * 384];
        __builtin_nontemporal_store(v0, (f4v*)&dst[j * 4]);
        __builtin_nontemporal_store(v1, (f4v*)&dst[(j + 48) * 4]);
    }
}

// ---------------------------------------------------------------------------
// Conv phase (device fn): conv1d(K=3,pad=1) MFMA GEMM + bias+LN+ReLU (+dot).
// R10-proven: tile 32(M) x 256(F) x BK=64, 4 waves, wave tile 32x64,
// dbuf swizzled LDS, pipelined stage(t+1)-before-compute(t), 1 barrier/step,
// XCD-swizzled block ids (512 blocks, 64 contiguous per XCD).
// ASRC 0: A reg-staged from f32 (inline bf16 cvt).  ASRC 1: global_load_lds.
// MODE 0: bf16 h to outp.  MODE 1: dpo[m]=dot(h,lin_w)+lin_b.
// ---------------------------------------------------------------------------
template<int DIN, int MODE, int ASRC>
static __device__ __forceinline__ void conv_phase(
    const void* __restrict__ Ainp, const u16* __restrict__ Wt,
    const float* __restrict__ cb, const float* __restrict__ g,
    const float* __restrict__ bb, const float* __restrict__ lw,
    const float* __restrict__ lbp, const u16* __restrict__ zbuf,
    void* __restrict__ outp,
    char* AsB0, char* BsB0, float* redS, float* redQ, float* redP)
{
    const int K = 3 * DIN, NT = K / 64;
    const int tid  = threadIdx.x;
    const int lane = tid & 63, wc = tid >> 6;
    const int lr = lane & 15, q4 = lane >> 4;
    const int sb = (blockIdx.x & 7) * 64 + (blockIdx.x >> 3);
    const int m0 = sb * 32;
    const int n  = m0 >> 9, l0 = m0 & 511;

    f4v acc[2][4];
    #pragma unroll
    for (int mi = 0; mi < 2; mi++)
        #pragma unroll
        for (int ni = 0; ni < 4; ni++) acc[mi][ni] = {0.f, 0.f, 0.f, 0.f};

    const int a_r    = tid >> 3;
    const int a_slot = (tid & 7) ^ (a_r & 7);
    const int b_r    = tid >> 3;
    const int b_slot = (tid & 7) ^ (b_r & 7);

    const int aoff0 = (lr) * 128;
    const int aoff1 = (16 + lr) * 128;
    int boff[4];
    #pragma unroll
    for (int ni = 0; ni < 4; ni++) boff[ni] = (64 * wc + 16 * ni + lr) * 128;
    const int slot0 = ((q4)     ^ (lr & 7)) << 4;
    const int slot1 = ((q4 | 4) ^ (lr & 7)) << 4;

    auto stage = [&](int buf, int t) {
        char* AsB = AsB0 + buf * 4096;
        char* BsB = BsB0 + buf * 32768;
        const int k0 = t * 64;
        const int kc = k0 / DIN;
        const int d0 = k0 - kc * DIN;
        const int lp = l0 + a_r + kc - 1;
        if (ASRC == 0) {
            f4v v0 = {0.f, 0.f, 0.f, 0.f}, v1 = v0;
            if (lp >= 0 && lp < 512) {
                const float* src = (const float*)Ainp
                    + ((size_t)((n << 9) + lp)) * DIN + d0 + (tid & 7) * 8;
                v0 = *(const f4v*)src;
                v1 = *(const f4v*)(src + 4);
            }
            u16x8 r;
            #pragma unroll
            for (int jj = 0; jj < 4; jj++) { r[jj] = f2bf(v0[jj]); r[4 + jj] = f2bf(v1[jj]); }
            *(u16x8*)(AsB + a_r * 128 + a_slot * 16) = r;
        } else {
            const u16* asrc = (lp >= 0 && lp < 512)
                ? ((const u16*)Ainp + ((size_t)((n << 9) + lp)) * DIN + d0 + a_slot * 8)
                : zbuf;
            __builtin_amdgcn_global_load_lds(
                (const __attribute__((address_space(1))) void*)asrc,
                (__attribute__((address_space(3))) void*)(AsB + tid * 16), 16, 0, 0);
        }
        const u16* bsrc = Wt + (size_t)b_r * K + k0 + b_slot * 8;
        #pragma unroll
        for (int q = 0; q < 8; q++) {
            __builtin_amdgcn_global_load_lds(
                (const __attribute__((address_space(1))) void*)(bsrc + (size_t)q * 32 * K),
                (__attribute__((address_space(3))) void*)(BsB + q * 4096 + tid * 16),
                16, 0, 0);
        }
    };

    auto compute = [&](int buf) {
        char* AsB = AsB0 + buf * 4096;
        char* BsB = BsB0 + buf * 32768;
        #pragma unroll
        for (int kk = 0; kk < 2; kk++) {
            const int sl = kk ? slot1 : slot0;
            s8v a0 = *(const s8v*)(AsB + aoff0 + sl);
            s8v a1 = *(const s8v*)(AsB + aoff1 + sl);
            s8v b0 = *(const s8v*)(BsB + boff[0] + sl);
            s8v b1 = *(const s8v*)(BsB + boff[1] + sl);
            s8v b2 = *(const s8v*)(BsB + boff[2] + sl);
            s8v b3 = *(const s8v*)(BsB + boff[3] + sl);
            acc[0][0] = __builtin_amdgcn_mfma_f32_16x16x32_bf16(a0, b0, acc[0][0], 0, 0, 0);
            acc[0][1] = __builtin_amdgcn_mfma_f32_16x16x32_bf16(a0, b1, acc[0][1], 0, 0, 0);
            acc[0][2] = __builtin_amdgcn_mfma_f32_16x16x32_bf16(a0, b2, acc[0][2], 0, 0, 0);
            acc[0][3] = __builtin_amdgcn_mfma_f32_16x16x32_bf16(a0, b3, acc[0][3], 0, 0, 0);
            acc[1][0] = __builtin_amdgcn_mfma_f32_16x16x32_bf16(a1, b0, acc[1][0], 0, 0, 0);
            acc[1][1] = __builtin_amdgcn_mfma_f32_16x16x32_bf16(a1, b1, acc[1][1], 0, 0, 0);
            acc[1][2] = __builtin_amdgcn_mfma_f32_16x16x32_bf16(a1, b2, acc[1][2], 0, 0, 0);
            acc[1][3] = __builtin_amdgcn_mfma_f32_16x16x32_bf16(a1, b3, acc[1][3], 0, 0, 0);
        }
    };

    stage(0, 0);
    __syncthreads();
    int cur = 0;
    for (int t = 0; t < NT; ++t) {
        if (t + 1 < NT) stage(cur ^ 1, t + 1);
        compute(cur);
        __syncthreads();
        cur ^= 1;
    }

    // ---- epilogue: bias + LN + ReLU (+ dot) ----
    float cbv[4], gv[4], bbv[4], lwv[4];
    int col[4];
    #pragma unroll
    for (int ni = 0; ni < 4; ni++) {
        col[ni] = 64 * wc + 16 * ni + lr;
        cbv[ni] = cb[col[ni]]; gv[ni] = g[col[ni]]; bbv[ni] = bb[col[ni]];
        if (MODE == 1) lwv[ni] = lw[col[ni]];
    }

    float sv[2][4], sq[2][4];
    #pragma unroll
    for (int mi = 0; mi < 2; mi++)
        #pragma unroll
        for (int reg = 0; reg < 4; reg++) {
            float s = 0.f, q = 0.f;
            #pragma unroll
            for (int ni = 0; ni < 4; ni++) {
                float v = acc[mi][ni][reg] + cbv[ni];
                s += v; q += v * v;
            }
            #pragma unroll
            for (int msk = 1; msk < 16; msk <<= 1) {
                s += __shfl_xor(s, msk);
                q += __shfl_xor(q, msk);
            }
            sv[mi][reg] = s; sq[mi][reg] = q;
        }
    if (lr == 0) {
        #pragma unroll
        for (int mi = 0; mi < 2; mi++)
            #pragma unroll
            for (int reg = 0; reg < 4; reg++) {
                int rl = 16 * mi + 4 * q4 + reg;
                redS[rl * 4 + wc] = sv[mi][reg];
                redQ[rl * 4 + wc] = sq[mi][reg];
            }
    }
    __syncthreads();

    float mean_[2][4], rs_[2][4];
    #pragma unroll
    for (int mi = 0; mi < 2; mi++)
        #pragma unroll
        for (int reg = 0; reg < 4; reg++) {
            int rl = 16 * mi + 4 * q4 + reg;
            float4 ps = *(float4*)&redS[rl * 4];
            float4 pq = *(float4*)&redQ[rl * 4];
            float mean = (ps.x + ps.y + ps.z + ps.w) * (1.f / 256.f);
            float var  = (pq.x + pq.y + pq.z + pq.w) * (1.f / 256.f) - mean * mean;
            mean_[mi][reg] = mean;
            rs_[mi][reg]   = rsqrtf(var + 1e-5f);
        }

    if (MODE == 0) {
        u16* hout = (u16*)outp;
        #pragma unroll
        for (int mi = 0; mi < 2; mi++)
            #pragma unroll
            for (int reg = 0; reg < 4; reg++) {
                int rl = 16 * mi + 4 * q4 + reg;
                #pragma unroll
                for (int ni = 0; ni < 4; ni++) {
                    float v = acc[mi][ni][reg] + cbv[ni];
                    float o = fmaxf(0.f, (v - mean_[mi][reg]) * rs_[mi][reg] * gv[ni] + bbv[ni]);
                    hout[(size_t)(m0 + rl) * 256 + col[ni]] = f2bf(o);
                }
            }
    } else {
        float pp[2][4];
        #pragma unroll
        for (int mi = 0; mi < 2; mi++)
            #pragma unroll
            for (int reg = 0; reg < 4; reg++) {
                float p = 0.f;
                #pragma unroll
                for (int ni = 0; ni < 4; ni++) {
                    float v = acc[mi][ni][reg] + cbv[ni];
                    float o = fmaxf(0.f, (v - mean_[mi][reg]) * rs_[mi][reg] * gv[ni] + bbv[ni]);
                    p += o * lwv[ni];
                }
                #pragma unroll
                for (int msk = 1; msk < 16; msk <<= 1) p += __shfl_xor(p, msk);
                pp[mi][reg] = p;
            }
        if (lr == 0) {
            #pragma unroll
            for (int mi = 0; mi < 2; mi++)
                #pragma unroll
                for (int reg = 0; reg < 4; reg++) {
                    int rl = 16 * mi + 4 * q4 + reg;
                    redP[rl * 4 + wc] = pp[mi][reg];
                }
        }
        __syncthreads();
        if (tid < 32) {
            float* dpo = (float*)outp;
            float4 p4 = *(float4*)&redP[tid * 4];
            dpo[m0 + tid] = p4.x + p4.y + p4.z + p4.w + lbp[0];
        }
    }
}

// ---------------------------------------------------------------------------
// Dispatch 2 (cooperative): conv1 -> grid.sync -> conv2.
// 512 blocks x 256 thr, ~73.8 KB LDS -> 2 blocks/CU, all co-resident.
// Both phases run at full proven occupancy (identical resource shape).
// ---------------------------------------------------------------------------
__global__ __launch_bounds__(256, 2) void conv_pair_kernel(
    const float* __restrict__ x,
    const float* __restrict__ cb1, const float* __restrict__ g1,
    const float* __restrict__ bb1,
    const float* __restrict__ cb2, const float* __restrict__ g2,
    const float* __restrict__ bb2,
    const float* __restrict__ lw, const float* __restrict__ lbp,
    const u16* __restrict__ Wt1, const u16* __restrict__ Wt2,
    u16* __restrict__ h1, const u16* __restrict__ zbuf,
    float* __restrict__ dpo)
{
    __shared__ __align__(128) char AsB0[2 * 32 * 128];    // 8 KB
    __shared__ __align__(128) char BsB0[2 * 256 * 128];   // 64 KB
    __shared__ float redS[32 * 4];
    __shared__ float redQ[32 * 4];
    __shared__ float redP[32 * 4];

    cooperative_groups::grid_group grid = cooperative_groups::this_grid();

    // phase 1: conv1 (f32 A inline-cvt, bf16 h1 out)
    conv_phase<384, 0, 0>((const void*)x, Wt1, cb1, g1, bb1, nullptr, nullptr,
                          zbuf, (void*)h1, AsB0, BsB0, redS, redQ, redP);
    __threadfence();       // h1 device-visible across XCDs (G16)
    grid.sync();

    // phase 2: conv2 (bf16 h1 in, dpo out)
    conv_phase<256, 1, 1>((const void*)h1, Wt2, cb2, g2, bb2, lw, lbp,
                          zbuf, (void*)dpo, AsB0, BsB0, redS, redQ, redP);
}

// ---------------------------------------------------------------------------
extern "C" void kernel_launch(void* const* d_in, const int* in_sizes, int n_in,
                              void* d_out, int out_size, void* d_ws, size_t ws_size,
                              hipStream_t stream) {
    const float* x   = (const float*)d_in[0];
    const float* w1  = (const float*)d_in[1];
    const float* b1  = (const float*)d_in[2];
    const float* g1  = (const float*)d_in[3];
    const float* bb1 = (const float*)d_in[4];
    const float* w2  = (const float*)d_in[5];
    const float* b2  = (const float*)d_in[6];
    const float* g2  = (const float*)d_in[7];
    const float* bb2 = (const float*)d_in[8];
    const float* lw  = (const float*)d_in[9];
    const float* lb  = (const float*)d_in[10];
    const int* target = (const int*)d_in[11];

    // ws layout (bytes): zbuf 128 | Wt1 589824 | Wt2 393216 | h1 8388608
    char* wsb  = (char*)d_ws;
    u16*  zbuf = (u16*)wsb;
    u16*  Wt1  = (u16*)(wsb + 128);
    u16*  Wt2  = (u16*)(wsb + 128 + 589824);
    u16*  h1   = (u16*)(wsb + 128 + 589824 + 393216);

    float* out0 = (float*)d_out;                  // [32, 2048, 384]
    float* dpo  = out0 + (size_t)32 * 2048 * 384; // [32, 512]

    // D1: gather (1024 blocks, self-contained scan) + weight prep + zbuf
    gather_prep_kernel<<<2944, 256, 0, stream>>>(
        x, target, w1, w2, Wt1, Wt2, zbuf, out0);

    // D2: cooperative conv1 -> sync -> conv2
    void* args[] = {
        (void*)&x,
        (void*)&b1, (void*)&g1, (void*)&bb1,
        (void*)&b2, (void*)&g2, (void*)&bb2,
        (void*)&lw, (void*)&lb,
        (void*)&Wt1, (void*)&Wt2, (void*)&h1, (void*)&zbuf,
        (void*)&dpo
    };
    hipLaunchCooperativeKernel((void*)conv_pair_kernel, dim3(512), dim3(256),
                               args, 0, stream);
}

// Round 12
// 74.183 us; speedup vs baseline: 2.5677x; 2.5677x over previous
//
#include <hip/hip_runtime.h>
#include <hip/hip_bf16.h>

#define NB   32
#define TMEL 2048

typedef unsigned short u16;
typedef short s8v __attribute__((ext_vector_type(8)));
typedef float f4v __attribute__((ext_vector_type(4)));
typedef u16 u16x8 __attribute__((ext_vector_type(8)));

static __device__ __forceinline__ u16 f2bf(float v) {
    __hip_bfloat16 h = __float2bfloat16(v);
    return *(u16*)&h;
}

// ---------------------------------------------------------------------------
// Dispatch 1: weight prep only (tiny).
//  b in [0,1152): Wt1 transpose.  b in [1152,1920): Wt2 transpose.
//  b==0, tid<8:   zbuf zeroing.
// Wt[f][kc*DIN + d] = bf16(w[f][d][kc]);  w is [256][DIN][3]
// ---------------------------------------------------------------------------
__global__ __launch_bounds__(256) void prep_kernel(
    const float* __restrict__ w1,
    const float* __restrict__ w2,
    u16* __restrict__ Wt1,
    u16* __restrict__ Wt2,
    u16* __restrict__ zbuf)
{
    const int b = blockIdx.x, tid = threadIdx.x;
    if (b == 0 && tid < 8) {
        u16x8 z = {0, 0, 0, 0, 0, 0, 0, 0};
        *(u16x8*)(zbuf + tid * 8) = z;
    }
    if (b < 1152) {
        const int K = 1152, DIN = 384;
        int e = b * 256 + tid;
        int f = e / K;
        int rem = e - f * K;
        int kc = rem / DIN;
        int d = rem - kc * DIN;
        Wt1[e] = f2bf(w1[f * K + d * 3 + kc]);
    } else {
        const int K = 768, DIN = 256;
        int e = (b - 1152) * 256 + tid;
        int f = e / K;
        int rem = e - f * K;
        int kc = rem / DIN;
        int d = rem - kc * DIN;
        Wt2[e] = f2bf(w2[f * K + d * 3 + kc]);
    }
}

// ---------------------------------------------------------------------------
// Fused conv1d(K=3,pad=1) MFMA GEMM + bias + LayerNorm + ReLU (+ lin dot),
// then a SEQUENTIAL gather tail (64 output rows per block).
// Conv: R10-proven tile 32(M) x 256(F) x BK=64, 256 thr = 4 waves, wave tile
// 32x64 (2x4 frags 16x16x32), dbuf swizzled LDS (74 KB -> 2 blocks/CU),
// pipelined stage(t+1)-before-compute(t), ONE barrier per K-step,
// XCD-swizzled block ids.  Gather tail reuses AsB LDS for the target scan;
// early-finishing blocks stream gather bytes while late blocks still MFMA
// (complementary pipes: conv is LDS/MFMA-bound at 2-5% HBM).
// ASRC 0: A reg-staged from f32 (inline bf16 cvt).  ASRC 1: global_load_lds.
// MODE 0: bf16 h to outp [M][256].  MODE 1: dpo[m]=dot(h,lin_w)+lin_b.
// ---------------------------------------------------------------------------
template<int DIN, int MODE, int ASRC>
__global__ __launch_bounds__(256, 2) void conv_mfma_kernel(
    const void* __restrict__ Ainp,  // f32 (ASRC=0) or bf16 (ASRC=1) [N*512][DIN]
    const u16* __restrict__ Wt,     // [256][3*DIN] bf16
    const float* __restrict__ cb,
    const float* __restrict__ g,
    const float* __restrict__ bb,
    const float* __restrict__ lw,
    const float* __restrict__ lbp,
    const u16* __restrict__ zbuf,
    void* __restrict__ outp,
    const float* __restrict__ xf,   // f32 x for gather
    const int* __restrict__ target,
    float* __restrict__ out0,
    int gbase)                      // first gathered output row for sb==0
{
    const int K = 3 * DIN, NT = K / 64;
    __shared__ __align__(128) char AsB[2][32 * 128];    // 2 x 4 KB
    __shared__ __align__(128) char BsB[2][256 * 128];   // 2 x 32 KB
    __shared__ float redS[32 * 4];
    __shared__ float redQ[32 * 4];
    __shared__ float redP[32 * 4];

    const int tid  = threadIdx.x;
    const int lane = tid & 63, wc = tid >> 6;          // 4 waves, col groups
    const int lr = lane & 15, q4 = lane >> 4;
    // XCD-aware bijective swizzle: 512 blocks, 8 XCDs, 64 contiguous per XCD
    const int sb = (blockIdx.x & 7) * 64 + (blockIdx.x >> 3);
    const int m0 = sb * 32;
    const int n  = m0 >> 9, l0 = m0 & 511;

    f4v acc[2][4];
    #pragma unroll
    for (int mi = 0; mi < 2; mi++)
        #pragma unroll
        for (int ni = 0; ni < 4; ni++) acc[mi][ni] = {0.f, 0.f, 0.f, 0.f};

    // staging maps (dest linear; source slot pre-swizzled, rule 21)
    const int a_r    = tid >> 3;                       // A row 0..31
    const int a_slot = (tid & 7) ^ (a_r & 7);
    const int b_r    = tid >> 3;                       // B row base 0..31
    const int b_slot = (tid & 7) ^ (b_r & 7);          // (q*32)&7==0 -> invariant

    // fragment read offsets (swizzled)
    const int aoff0 = (lr) * 128;
    const int aoff1 = (16 + lr) * 128;
    int boff[4];
    #pragma unroll
    for (int ni = 0; ni < 4; ni++) boff[ni] = (64 * wc + 16 * ni + lr) * 128;
    const int slot0 = ((q4)     ^ (lr & 7)) << 4;
    const int slot1 = ((q4 | 4) ^ (lr & 7)) << 4;

    auto stage = [&](int buf, int t) {
        const int k0 = t * 64;
        const int kc = k0 / DIN;
        const int d0 = k0 - kc * DIN;
        const int lp = l0 + a_r + kc - 1;
        if (ASRC == 0) {
            // reg-stage A from f32: load 8 f32, cvt, swizzled ds_write_b128
            f4v v0 = {0.f, 0.f, 0.f, 0.f}, v1 = v0;
            if (lp >= 0 && lp < 512) {
                const float* src = (const float*)Ainp
                    + ((size_t)((n << 9) + lp)) * DIN + d0 + (tid & 7) * 8;
                v0 = *(const f4v*)src;
                v1 = *(const f4v*)(src + 4);
            }
            u16x8 r;
            #pragma unroll
            for (int jj = 0; jj < 4; jj++) { r[jj] = f2bf(v0[jj]); r[4 + jj] = f2bf(v1[jj]); }
            *(u16x8*)(AsB[buf] + a_r * 128 + a_slot * 16) = r;
        } else {
            const u16* asrc = (lp >= 0 && lp < 512)
                ? ((const u16*)Ainp + ((size_t)((n << 9) + lp)) * DIN + d0 + a_slot * 8)
                : zbuf;
            __builtin_amdgcn_global_load_lds(
                (const __attribute__((address_space(1))) void*)asrc,
                (__attribute__((address_space(3))) void*)(AsB[buf] + tid * 16), 16, 0, 0);
        }
        const u16* bsrc = Wt + (size_t)b_r * K + k0 + b_slot * 8;
        #pragma unroll
        for (int q = 0; q < 8; q++) {
            __builtin_amdgcn_global_load_lds(
                (const __attribute__((address_space(1))) void*)(bsrc + (size_t)q * 32 * K),
                (__attribute__((address_space(3))) void*)(BsB[buf] + q * 4096 + tid * 16),
                16, 0, 0);
        }
    };

    auto compute = [&](int buf) {
        #pragma unroll
        for (int kk = 0; kk < 2; kk++) {
            const int sl = kk ? slot1 : slot0;
            s8v a0 = *(const s8v*)(AsB[buf] + aoff0 + sl);
            s8v a1 = *(const s8v*)(AsB[buf] + aoff1 + sl);
            s8v b0 = *(const s8v*)(BsB[buf] + boff[0] + sl);
            s8v b1 = *(const s8v*)(BsB[buf] + boff[1] + sl);
            s8v b2 = *(const s8v*)(BsB[buf] + boff[2] + sl);
            s8v b3 = *(const s8v*)(BsB[buf] + boff[3] + sl);
            acc[0][0] = __builtin_amdgcn_mfma_f32_16x16x32_bf16(a0, b0, acc[0][0], 0, 0, 0);
            acc[0][1] = __builtin_amdgcn_mfma_f32_16x16x32_bf16(a0, b1, acc[0][1], 0, 0, 0);
            acc[0][2] = __builtin_amdgcn_mfma_f32_16x16x32_bf16(a0, b2, acc[0][2], 0, 0, 0);
            acc[0][3] = __builtin_amdgcn_mfma_f32_16x16x32_bf16(a0, b3, acc[0][3], 0, 0, 0);
            acc[1][0] = __builtin_amdgcn_mfma_f32_16x16x32_bf16(a1, b0, acc[1][0], 0, 0, 0);
            acc[1][1] = __builtin_amdgcn_mfma_f32_16x16x32_bf16(a1, b1, acc[1][1], 0, 0, 0);
            acc[1][2] = __builtin_amdgcn_mfma_f32_16x16x32_bf16(a1, b2, acc[1][2], 0, 0, 0);
            acc[1][3] = __builtin_amdgcn_mfma_f32_16x16x32_bf16(a1, b3, acc[1][3], 0, 0, 0);
        }
    };

    // pipelined main loop: one barrier per K-step, stage(t+1) overlaps compute(t)
    stage(0, 0);
    __syncthreads();
    int cur = 0;
    for (int t = 0; t < NT; ++t) {
        if (t + 1 < NT) stage(cur ^ 1, t + 1);
        compute(cur);
        __syncthreads();
        cur ^= 1;
    }

    // ---- epilogue: bias + LN + ReLU (+ dot) ----
    // acc[mi][ni][reg] = C[m0 + 16mi + 4*q4 + reg][64wc + 16ni + lr]
    float cbv[4], gv[4], bbv[4], lwv[4];
    int col[4];
    #pragma unroll
    for (int ni = 0; ni < 4; ni++) {
        col[ni] = 64 * wc + 16 * ni + lr;
        cbv[ni] = cb[col[ni]]; gv[ni] = g[col[ni]]; bbv[ni] = bb[col[ni]];
        if (MODE == 1) lwv[ni] = lw[col[ni]];
    }

    float sv[2][4], sq[2][4];
    #pragma unroll
    for (int mi = 0; mi < 2; mi++)
        #pragma unroll
        for (int reg = 0; reg < 4; reg++) {
            float s = 0.f, q = 0.f;
            #pragma unroll
            for (int ni = 0; ni < 4; ni++) {
                float v = acc[mi][ni][reg] + cbv[ni];
                s += v; q += v * v;
            }
            #pragma unroll
            for (int msk = 1; msk < 16; msk <<= 1) {
                s += __shfl_xor(s, msk);
                q += __shfl_xor(q, msk);
            }
            sv[mi][reg] = s; sq[mi][reg] = q;
        }
    if (lr == 0) {
        #pragma unroll
        for (int mi = 0; mi < 2; mi++)
            #pragma unroll
            for (int reg = 0; reg < 4; reg++) {
                int rl = 16 * mi + 4 * q4 + reg;
                redS[rl * 4 + wc] = sv[mi][reg];
                redQ[rl * 4 + wc] = sq[mi][reg];
            }
    }
    __syncthreads();

    float mean_[2][4], rs_[2][4];
    #pragma unroll
    for (int mi = 0; mi < 2; mi++)
        #pragma unroll
        for (int reg = 0; reg < 4; reg++) {
            int rl = 16 * mi + 4 * q4 + reg;
            float4 ps = *(float4*)&redS[rl * 4];
            float4 pq = *(float4*)&redQ[rl * 4];
            float mean = (ps.x + ps.y + ps.z + ps.w) * (1.f / 256.f);
            float var  = (pq.x + pq.y + pq.z + pq.w) * (1.f / 256.f) - mean * mean;
            mean_[mi][reg] = mean;
            rs_[mi][reg]   = rsqrtf(var + 1e-5f);
        }

    if (MODE == 0) {
        u16* hout = (u16*)outp;
        #pragma unroll
        for (int mi = 0; mi < 2; mi++)
            #pragma unroll
            for (int reg = 0; reg < 4; reg++) {
                int rl = 16 * mi + 4 * q4 + reg;
                #pragma unroll
                for (int ni = 0; ni < 4; ni++) {
                    float v = acc[mi][ni][reg] + cbv[ni];
                    float o = fmaxf(0.f, (v - mean_[mi][reg]) * rs_[mi][reg] * gv[ni] + bbv[ni]);
                    hout[(size_t)(m0 + rl) * 256 + col[ni]] = f2bf(o);
                }
            }
    } else {
        float pp[2][4];
        #pragma unroll
        for (int mi = 0; mi < 2; mi++)
            #pragma unroll
            for (int reg = 0; reg < 4; reg++) {
                float p = 0.f;
                #pragma unroll
                for (int ni = 0; ni < 4; ni++) {
                    float v = acc[mi][ni][reg] + cbv[ni];
                    float o = fmaxf(0.f, (v - mean_[mi][reg]) * rs_[mi][reg] * gv[ni] + bbv[ni]);
                    p += o * lwv[ni];
                }
                #pragma unroll
                for (int msk = 1; msk < 16; msk <<= 1) p += __shfl_xor(p, msk);
                pp[mi][reg] = p;
            }
        if (lr == 0) {
            #pragma unroll
            for (int mi = 0; mi < 2; mi++)
                #pragma unroll
                for (int reg = 0; reg < 4; reg++) {
                    int rl = 16 * mi + 4 * q4 + reg;
                    redP[rl * 4 + wc] = pp[mi][reg];
                }
        }
        __syncthreads();
        if (tid < 32) {
            float* dpo = (float*)outp;
            float4 p4 = *(float4*)&redP[tid * 4];
            dpo[m0 + tid] = p4.x + p4.y + p4.z + p4.w + lbp[0];
        }
    }

    // ---- gather tail: 64 output rows for this block ----
    __syncthreads();                        // conv LDS reads done; reuse AsB
    int* c    = (int*)(AsB[0]);             // 512 ints = 2 KB
    int* ridx = (int*)(AsB[0] + 2048);      // 64 ints
    const int grow0 = gbase + sb * 64;      // 64-row chunk, batch-aligned
    const int ng    = grow0 >> 11;
    c[tid]       = target[ng * 512 + tid];
    c[tid + 256] = target[ng * 512 + 256 + tid];
    __syncthreads();
    for (int off = 1; off < 512; off <<= 1) {
        int v0 = (tid       >= off) ? c[tid       - off] : 0;
        int v1 = (tid + 256 >= off) ? c[tid + 256 - off] : 0;
        __syncthreads();
        c[tid]       += v0;
        c[tid + 256] += v1;
        __syncthreads();
    }
    const int total = c[511];
    if (tid < 64) {
        int t = (grow0 & 2047) + tid;
        int lo = 0, hi = 512;
        while (lo < hi) {
            int mid = (lo + hi) >> 1;
            if (c[mid] <= t) lo = mid + 1; else hi = mid;
        }
        ridx[tid] = (t < total) ? min(lo, 511) : -1;
    }
    __syncthreads();

    const size_t xbase = (size_t)(ng << 9) * 384;
    const size_t obase = (size_t)grow0 * 384;
    #pragma unroll 4
    for (int it = 0; it < 12; ++it) {
        int u  = tid + it * 256;            // 3072 units = 64 rows x 48
        int j  = u % 48;
        int rl = u / 48;
        int ie = ridx[rl];
        f4v v0 = {0.f, 0.f, 0.f, 0.f}, v1 = v0;
        if (ie >= 0) {
            const float* src = &xf[xbase + (size_t)ie * 384];
            v0 = *(const f4v*)&src[j * 4];
            v1 = *(const f4v*)&src[(j + 48) * 4];
        }
        float* dst = &out0[obase + (size_t)rl * 384];
        __builtin_nontemporal_store(v0, (f4v*)&dst[j * 4]);
        __builtin_nontemporal_store(v1, (f4v*)&dst[(j + 48) * 4]);
    }
}

// ---------------------------------------------------------------------------
extern "C" void kernel_launch(void* const* d_in, const int* in_sizes, int n_in,
                              void* d_out, int out_size, void* d_ws, size_t ws_size,
                              hipStream_t stream) {
    const float* x   = (const float*)d_in[0];
    const float* w1  = (const float*)d_in[1];
    const float* b1  = (const float*)d_in[2];
    const float* g1  = (const float*)d_in[3];
    const float* bb1 = (const float*)d_in[4];
    const float* w2  = (const float*)d_in[5];
    const float* b2  = (const float*)d_in[6];
    const float* g2  = (const float*)d_in[7];
    const float* bb2 = (const float*)d_in[8];
    const float* lw  = (const float*)d_in[9];
    const float* lb  = (const float*)d_in[10];
    const int* target = (const int*)d_in[11];

    // ws layout (bytes): zbuf 128 | Wt1 589824 | Wt2 393216 | h1 8388608
    char* wsb  = (char*)d_ws;
    u16*  zbuf = (u16*)wsb;
    u16*  Wt1  = (u16*)(wsb + 128);
    u16*  Wt2  = (u16*)(wsb + 128 + 589824);
    u16*  h1   = (u16*)(wsb + 128 + 589824 + 393216);

    float* out0 = (float*)d_out;                  // [32, 2048, 384]
    float* dpo  = out0 + (size_t)32 * 2048 * 384; // [32, 512]

    // D1: weight prep + zbuf (tiny)
    prep_kernel<<<1920, 256, 0, stream>>>(w1, w2, Wt1, Wt2, zbuf);

    // D2: conv1 (f32 A, inline cvt) + gather rows [0, 32768)
    conv_mfma_kernel<384, 0, 0><<<512, 256, 0, stream>>>(
        (const void*)x, Wt1, b1, g1, bb1, nullptr, nullptr, zbuf, (void*)h1,
        x, target, out0, 0);

    // D3: conv2 (bf16 h1 in, dpo out) + gather rows [32768, 65536)
    conv_mfma_kernel<256, 1, 1><<<512, 256, 0, stream>>>(
        (const void*)h1, Wt2, b2, g2, bb2, lw, lb, zbuf, (void*)dpo,
        x, target, out0, 32768);
}

// Round 13
// 70.105 us; speedup vs baseline: 2.7171x; 1.0582x over previous
//
#include <hip/hip_runtime.h>
#include <hip/hip_bf16.h>

typedef unsigned short u16;
typedef short s8v __attribute__((ext_vector_type(8)));
typedef float f4v __attribute__((ext_vector_type(4)));
typedef u16 u16x8 __attribute__((ext_vector_type(8)));

static __device__ __forceinline__ u16 f2bf(float v) {
    __hip_bfloat16 h = __float2bfloat16(v);
    return *(u16*)&h;
}

// ---------------------------------------------------------------------------
// Dispatch 1: gather + weight prep (R10-proven, no cross-block deps).
//  b in [0,1024):    gather role (block re-scans its batch's target).
//  b in [1024,2176): Wt1 transpose.  b in [2176,2944): Wt2 transpose.
// Wt[f][kc*DIN + d] = bf16(w[f][d][kc]);  w is [256][DIN][3]
// ---------------------------------------------------------------------------
__global__ __launch_bounds__(256) void gather_prep_kernel(
    const float* __restrict__ x,
    const int*   __restrict__ target,
    const float* __restrict__ w1,
    const float* __restrict__ w2,
    u16* __restrict__ Wt1,
    u16* __restrict__ Wt2,
    float* __restrict__ out0)
{
    __shared__ int c[512];
    __shared__ int ridx[64];
    const int b = blockIdx.x, tid = threadIdx.x;

    if (b >= 1024) {
        if (b < 2176) {
            const int K = 1152, DIN = 384;
            int e = (b - 1024) * 256 + tid;
            int f = e / K;
            int rem = e - f * K;
            int kc = rem / DIN;
            int d = rem - kc * DIN;
            Wt1[e] = f2bf(w1[f * K + d * 3 + kc]);
        } else {
            const int K = 768, DIN = 256;
            int e = (b - 2176) * 256 + tid;
            int f = e / K;
            int rem = e - f * K;
            int kc = rem / DIN;
            int d = rem - kc * DIN;
            Wt2[e] = f2bf(w2[f * K + d * 3 + kc]);
        }
        return;
    }

    // ---- gather role ----
    const int n = b >> 5, sub = b & 31;
    c[tid]       = target[n * 512 + tid];
    c[tid + 256] = target[n * 512 + 256 + tid];
    __syncthreads();
    for (int off = 1; off < 512; off <<= 1) {
        int v0 = (tid       >= off) ? c[tid       - off] : 0;
        int v1 = (tid + 256 >= off) ? c[tid + 256 - off] : 0;
        __syncthreads();
        c[tid]       += v0;
        c[tid + 256] += v1;
        __syncthreads();
    }
    const int total = c[511];
    if (tid < 64) {
        int t = sub * 64 + tid;
        int lo = 0, hi = 512;
        while (lo < hi) {
            int mid = (lo + hi) >> 1;
            if (c[mid] <= t) lo = mid + 1; else hi = mid;
        }
        ridx[tid] = (t < total) ? min(lo, 511) : -1;
    }
    __syncthreads();

    const size_t xbase = (size_t)(n << 9) * 384;
    const size_t obase = ((size_t)(n << 11) + sub * 64) * 384;
    #pragma unroll 4
    for (int it = 0; it < 12; ++it) {
        int u  = tid + it * 256;
        int j  = u % 48;
        int rl = u / 48;
        int ie = ridx[rl];
        f4v v0 = {0.f, 0.f, 0.f, 0.f}, v1 = v0;
        if (ie >= 0) {
            const float* src = &x[xbase + (size_t)ie * 384];
            v0 = *(const f4v*)&src[j * 4];
            v1 = *(const f4v*)&src[(j + 48) * 4];
        }
        float* dst = &out0[obase + (size_t)rl * 384];
        __builtin_nontemporal_store(v0, (f4v*)&dst[j * 4]);
        __builtin_nontemporal_store(v1, (f4v*)&dst[(j + 48) * 4]);
    }
}

// ---------------------------------------------------------------------------
// Dispatch 2: FUSED conv1 -> LN1/ReLU -> h1 in LDS -> conv2 -> LN2/ReLU -> dot
// Per block (512 blocks, XCD-swizzled, 256 thr = 4 waves, 2 blocks/CU):
//  P1: conv1 over a 48-row window [l0-8, l0+40) (3 m-frags/wave, BK=64,
//      A reg-staged f32->bf16 dbuf, B=Wt1 global_load_lds dbuf, pipelined,
//      one barrier/K-step — R10-proven schedule).
//  LN1 epilogue writes the 34 valid rows [l0-1, l0+33) as bf16 into
//      swizzled h1 LDS (rows outside [0,512) are ZERO = conv pad).
//      Halo rows are recomputed redundantly; deterministic => bitwise equal.
//  P2: conv2 (K=768, 12 BK=64 steps, B=Wt2 single-buffered at dead B-buf1,
//      A-frags read DIRECTLY from h1 LDS) -> LN2/ReLU/dot -> dpo.
// LDS liveness (79872 B declared -> 2 blocks/CU):
//  [0,65536)      P1 B-dbuf | P2: h1 [0,17408), Bs2 [32768,65536)
//  [65536,77824)  P1 A-dbuf (dead in P2)
//  [77824,79872)  redS[192] | redQ[192] | redP[128]
// ---------------------------------------------------------------------------
__global__ __launch_bounds__(256, 2) void fused_conv_kernel(
    const float* __restrict__ x,
    const u16* __restrict__ Wt1,   // [256][1152]
    const u16* __restrict__ Wt2,   // [256][768]
    const float* __restrict__ cb1, const float* __restrict__ g1,
    const float* __restrict__ bb1,
    const float* __restrict__ cb2, const float* __restrict__ g2,
    const float* __restrict__ bb2,
    const float* __restrict__ lw, const float* __restrict__ lbp,
    float* __restrict__ dpo)
{
    __shared__ __align__(128) char LDS[79872];
    float* redS = (float*)(LDS + 77824);   // [48*4]
    float* redQ = (float*)(LDS + 78592);   // [48*4]
    float* redP = (float*)(LDS + 79360);   // [32*4]

    const int tid  = threadIdx.x;
    const int lane = tid & 63, wc = tid >> 6;
    const int lr = lane & 15, q4 = lane >> 4;
    const int sb = (blockIdx.x & 7) * 64 + (blockIdx.x >> 3);
    const int m0 = sb * 32;
    const int n  = m0 >> 9, l0 = m0 & 511;

    // B staging map (both phases): dest linear tid*16, source slot swizzled
    const int b_r    = tid >> 3;
    const int b_slot = (tid & 7) ^ (b_r & 7);
    // fragment read offsets (B rows 128 B, slot ^= lr&7 — proven)
    int boff[4];
    #pragma unroll
    for (int ni = 0; ni < 4; ni++) boff[ni] = (64 * wc + 16 * ni + lr) * 128;
    const int slot0 = ((q4)     ^ (lr & 7)) << 4;
    const int slot1 = ((q4 | 4) ^ (lr & 7)) << 4;

    // ================= P1: conv1 over 48-row window =================
    f4v acc[3][4];
    #pragma unroll
    for (int mi = 0; mi < 3; mi++)
        #pragma unroll
        for (int ni = 0; ni < 4; ni++) acc[mi][ni] = {0.f, 0.f, 0.f, 0.f};

    auto stage1 = [&](int buf, int t) {
        const int k0 = t * 64;
        const int kc = k0 / 384;
        const int d0 = k0 - kc * 384;
        char* As = LDS + 65536 + buf * 6144;
        for (int u = tid; u < 384; u += 256) {
            int ar = u >> 3;                       // window row 0..47
            int aslot = (u & 7) ^ (ar & 7);
            int lp = l0 - 8 + ar + kc - 1;
            f4v v0 = {0.f, 0.f, 0.f, 0.f}, v1 = v0;
            if (lp >= 0 && lp < 512) {
                const float* src = x + ((size_t)((n << 9) + lp)) * 384 + d0 + (u & 7) * 8;
                v0 = *(const f4v*)src;
                v1 = *(const f4v*)(src + 4);
            }
            u16x8 r;
            #pragma unroll
            for (int jj = 0; jj < 4; jj++) { r[jj] = f2bf(v0[jj]); r[4 + jj] = f2bf(v1[jj]); }
            *(u16x8*)(As + ar * 128 + aslot * 16) = r;
        }
        const u16* bsrc = Wt1 + (size_t)b_r * 1152 + k0 + b_slot * 8;
        #pragma unroll
        for (int q = 0; q < 8; q++) {
            __builtin_amdgcn_global_load_lds(
                (const __attribute__((address_space(1))) void*)(bsrc + (size_t)q * 32 * 1152),
                (__attribute__((address_space(3))) void*)(LDS + buf * 32768 + q * 4096 + tid * 16),
                16, 0, 0);
        }
    };

    auto compute1 = [&](int buf) {
        char* As = LDS + 65536 + buf * 6144;
        char* Bs = LDS + buf * 32768;
        #pragma unroll
        for (int kk = 0; kk < 2; kk++) {
            const int sl = kk ? slot1 : slot0;
            s8v a0 = *(const s8v*)(As + (lr) * 128 + sl);
            s8v a1 = *(const s8v*)(As + (16 + lr) * 128 + sl);
            s8v a2 = *(const s8v*)(As + (32 + lr) * 128 + sl);
            s8v b0 = *(const s8v*)(Bs + boff[0] + sl);
            s8v b1 = *(const s8v*)(Bs + boff[1] + sl);
            s8v b2 = *(const s8v*)(Bs + boff[2] + sl);
            s8v b3 = *(const s8v*)(Bs + boff[3] + sl);
            acc[0][0] = __builtin_amdgcn_mfma_f32_16x16x32_bf16(a0, b0, acc[0][0], 0, 0, 0);
            acc[0][1] = __builtin_amdgcn_mfma_f32_16x16x32_bf16(a0, b1, acc[0][1], 0, 0, 0);
            acc[0][2] = __builtin_amdgcn_mfma_f32_16x16x32_bf16(a0, b2, acc[0][2], 0, 0, 0);
            acc[0][3] = __builtin_amdgcn_mfma_f32_16x16x32_bf16(a0, b3, acc[0][3], 0, 0, 0);
            acc[1][0] = __builtin_amdgcn_mfma_f32_16x16x32_bf16(a1, b0, acc[1][0], 0, 0, 0);
            acc[1][1] = __builtin_amdgcn_mfma_f32_16x16x32_bf16(a1, b1, acc[1][1], 0, 0, 0);
            acc[1][2] = __builtin_amdgcn_mfma_f32_16x16x32_bf16(a1, b2, acc[1][2], 0, 0, 0);
            acc[1][3] = __builtin_amdgcn_mfma_f32_16x16x32_bf16(a1, b3, acc[1][3], 0, 0, 0);
            acc[2][0] = __builtin_amdgcn_mfma_f32_16x16x32_bf16(a2, b0, acc[2][0], 0, 0, 0);
            acc[2][1] = __builtin_amdgcn_mfma_f32_16x16x32_bf16(a2, b1, acc[2][1], 0, 0, 0);
            acc[2][2] = __builtin_amdgcn_mfma_f32_16x16x32_bf16(a2, b2, acc[2][2], 0, 0, 0);
            acc[2][3] = __builtin_amdgcn_mfma_f32_16x16x32_bf16(a2, b3, acc[2][3], 0, 0, 0);
        }
    };

    stage1(0, 0);
    __syncthreads();
    int cur = 0;
    for (int t = 0; t < 18; ++t) {
        if (t + 1 < 18) stage1(cur ^ 1, t + 1);
        compute1(cur);
        __syncthreads();
        cur ^= 1;
    }

    // ---- P1 epilogue: bias + LN1 + ReLU -> h1 LDS (34 rows, swizzled) ----
    int col[4];
    float cbv[4], gv[4], bbv[4];
    #pragma unroll
    for (int ni = 0; ni < 4; ni++) {
        col[ni] = 64 * wc + 16 * ni + lr;
        cbv[ni] = cb1[col[ni]]; gv[ni] = g1[col[ni]]; bbv[ni] = bb1[col[ni]];
    }

    #pragma unroll
    for (int mi = 0; mi < 3; mi++)
        #pragma unroll
        for (int reg = 0; reg < 4; reg++) {
            float s = 0.f, q = 0.f;
            #pragma unroll
            for (int ni = 0; ni < 4; ni++) {
                float v = acc[mi][ni][reg] + cbv[ni];
                s += v; q += v * v;
            }
            #pragma unroll
            for (int msk = 1; msk < 16; msk <<= 1) {
                s += __shfl_xor(s, msk);
                q += __shfl_xor(q, msk);
            }
            if (lr == 0) {
                int rl = 16 * mi + 4 * q4 + reg;
                redS[rl * 4 + wc] = s;
                redQ[rl * 4 + wc] = q;
            }
        }
    __syncthreads();

    #pragma unroll
    for (int mi = 0; mi < 3; mi++)
        #pragma unroll
        for (int reg = 0; reg < 4; reg++) {
            int rl = 16 * mi + 4 * q4 + reg;
            int h  = rl - 7;
            if (h >= 0 && h < 34) {
                float4 ps = *(float4*)&redS[rl * 4];
                float4 pq = *(float4*)&redQ[rl * 4];
                float mean = (ps.x + ps.y + ps.z + ps.w) * (1.f / 256.f);
                float var  = (pq.x + pq.y + pq.z + pq.w) * (1.f / 256.f) - mean * mean;
                float rs   = rsqrtf(var + 1e-5f);
                int l = l0 - 8 + rl;
                bool lv = (l >= 0 && l < 512);
                #pragma unroll
                for (int ni = 0; ni < 4; ni++) {
                    float v = acc[mi][ni][reg] + cbv[ni];
                    float o = lv ? fmaxf(0.f, (v - mean) * rs * gv[ni] + bbv[ni]) : 0.f;
                    int slot = (col[ni] >> 3) ^ (h & 7);
                    *(u16*)(LDS + h * 512 + slot * 16 + (col[ni] & 7) * 2) = f2bf(o);
                }
            }
        }

    // ================= P2: conv2 (A from h1 LDS, B=Wt2 single-buf) ========
    f4v acc2[2][4];
    #pragma unroll
    for (int mi = 0; mi < 2; mi++)
        #pragma unroll
        for (int ni = 0; ni < 4; ni++) acc2[mi][ni] = {0.f, 0.f, 0.f, 0.f};

    for (int t2 = 0; t2 < 12; ++t2) {
        __syncthreads();   // t2=0: h1 visible; else: prev Bs2 reads done
        const int k0 = t2 * 64;
        const u16* bsrc = Wt2 + (size_t)b_r * 768 + k0 + b_slot * 8;
        #pragma unroll
        for (int q = 0; q < 8; q++) {
            __builtin_amdgcn_global_load_lds(
                (const __attribute__((address_space(1))) void*)(bsrc + (size_t)q * 32 * 768),
                (__attribute__((address_space(3))) void*)(LDS + 32768 + q * 4096 + tid * 16),
                16, 0, 0);
        }
        __syncthreads();   // compiler drains vmcnt before barrier

        const int kc2   = t2 >> 2;
        const int sbase = 8 * (t2 & 3);
        #pragma unroll
        for (int kk = 0; kk < 2; kk++) {
            const int sl = kk ? slot1 : slot0;
            char* Bs = LDS + 32768;
            s8v b0 = *(const s8v*)(Bs + boff[0] + sl);
            s8v b1 = *(const s8v*)(Bs + boff[1] + sl);
            s8v b2 = *(const s8v*)(Bs + boff[2] + sl);
            s8v b3 = *(const s8v*)(Bs + boff[3] + sl);
            s8v a0, a1;
            {
                int h = lr + kc2;
                int s = sbase + 4 * kk + q4;
                a0 = *(const s8v*)(LDS + h * 512 + ((s ^ (h & 7)) << 4));
                h = 16 + lr + kc2;
                a1 = *(const s8v*)(LDS + h * 512 + ((s ^ (h & 7)) << 4));
            }
            acc2[0][0] = __builtin_amdgcn_mfma_f32_16x16x32_bf16(a0, b0, acc2[0][0], 0, 0, 0);
            acc2[0][1] = __builtin_amdgcn_mfma_f32_16x16x32_bf16(a0, b1, acc2[0][1], 0, 0, 0);
            acc2[0][2] = __builtin_amdgcn_mfma_f32_16x16x32_bf16(a0, b2, acc2[0][2], 0, 0, 0);
            acc2[0][3] = __builtin_amdgcn_mfma_f32_16x16x32_bf16(a0, b3, acc2[0][3], 0, 0, 0);
            acc2[1][0] = __builtin_amdgcn_mfma_f32_16x16x32_bf16(a1, b0, acc2[1][0], 0, 0, 0);
            acc2[1][1] = __builtin_amdgcn_mfma_f32_16x16x32_bf16(a1, b1, acc2[1][1], 0, 0, 0);
            acc2[1][2] = __builtin_amdgcn_mfma_f32_16x16x32_bf16(a1, b2, acc2[1][2], 0, 0, 0);
            acc2[1][3] = __builtin_amdgcn_mfma_f32_16x16x32_bf16(a1, b3, acc2[1][3], 0, 0, 0);
        }
    }

    // ---- P2 epilogue: bias + LN2 + ReLU + dot(lin_w) -> dpo ----
    float cbv2[4], gv2[4], bbv2[4], lwv[4];
    #pragma unroll
    for (int ni = 0; ni < 4; ni++) {
        cbv2[ni] = cb2[col[ni]]; gv2[ni] = g2[col[ni]]; bbv2[ni] = bb2[col[ni]];
        lwv[ni]  = lw[col[ni]];
    }

    float sv[2][4], sq[2][4];
    #pragma unroll
    for (int mi = 0; mi < 2; mi++)
        #pragma unroll
        for (int reg = 0; reg < 4; reg++) {
            float s = 0.f, q = 0.f;
            #pragma unroll
            for (int ni = 0; ni < 4; ni++) {
                float v = acc2[mi][ni][reg] + cbv2[ni];
                s += v; q += v * v;
            }
            #pragma unroll
            for (int msk = 1; msk < 16; msk <<= 1) {
                s += __shfl_xor(s, msk);
                q += __shfl_xor(q, msk);
            }
            sv[mi][reg] = s; sq[mi][reg] = q;
        }
    __syncthreads();            // Bs2/h1 reads done; reuse redS/redQ
    if (lr == 0) {
        #pragma unroll
        for (int mi = 0; mi < 2; mi++)
            #pragma unroll
            for (int reg = 0; reg < 4; reg++) {
                int rl = 16 * mi + 4 * q4 + reg;
                redS[rl * 4 + wc] = sv[mi][reg];
                redQ[rl * 4 + wc] = sq[mi][reg];
            }
    }
    __syncthreads();

    float pp[2][4];
    #pragma unroll
    for (int mi = 0; mi < 2; mi++)
        #pragma unroll
        for (int reg = 0; reg < 4; reg++) {
            int rl = 16 * mi + 4 * q4 + reg;
            float4 ps = *(float4*)&redS[rl * 4];
            float4 pq = *(float4*)&redQ[rl * 4];
            float mean = (ps.x + ps.y + ps.z + ps.w) * (1.f / 256.f);
            float var  = (pq.x + pq.y + pq.z + pq.w) * (1.f / 256.f) - mean * mean;
            float rs   = rsqrtf(var + 1e-5f);
            float p = 0.f;
            #pragma unroll
            for (int ni = 0; ni < 4; ni++) {
                float v = acc2[mi][ni][reg] + cbv2[ni];
                float o = fmaxf(0.f, (v - mean) * rs * gv2[ni] + bbv2[ni]);
                p += o * lwv[ni];
            }
            #pragma unroll
            for (int msk = 1; msk < 16; msk <<= 1) p += __shfl_xor(p, msk);
            pp[mi][reg] = p;
        }
    if (lr == 0) {
        #pragma unroll
        for (int mi = 0; mi < 2; mi++)
            #pragma unroll
            for (int reg = 0; reg < 4; reg++) {
                int rl = 16 * mi + 4 * q4 + reg;
                redP[rl * 4 + wc] = pp[mi][reg];
            }
    }
    __syncthreads();
    if (tid < 32) {
        float4 p4 = *(float4*)&redP[tid * 4];
        dpo[m0 + tid] = p4.x + p4.y + p4.z + p4.w + lbp[0];
    }
}

// ---------------------------------------------------------------------------
extern "C" void kernel_launch(void* const* d_in, const int* in_sizes, int n_in,
                              void* d_out, int out_size, void* d_ws, size_t ws_size,
                              hipStream_t stream) {
    const float* x   = (const float*)d_in[0];
    const float* w1  = (const float*)d_in[1];
    const float* b1  = (const float*)d_in[2];
    const float* g1  = (const float*)d_in[3];
    const float* bb1 = (const float*)d_in[4];
    const float* w2  = (const float*)d_in[5];
    const float* b2  = (const float*)d_in[6];
    const float* g2  = (const float*)d_in[7];
    const float* bb2 = (const float*)d_in[8];
    const float* lw  = (const float*)d_in[9];
    const float* lb  = (const float*)d_in[10];
    const int* target = (const int*)d_in[11];

    // ws layout (bytes): Wt1 589824 | Wt2 393216
    char* wsb = (char*)d_ws;
    u16*  Wt1 = (u16*)wsb;
    u16*  Wt2 = (u16*)(wsb + 589824);

    float* out0 = (float*)d_out;                  // [32, 2048, 384]
    float* dpo  = out0 + (size_t)32 * 2048 * 384; // [32, 512]

    // D1: gather (1024 blocks, self-contained scan) + weight prep
    gather_prep_kernel<<<2944, 256, 0, stream>>>(
        x, target, w1, w2, Wt1, Wt2, out0);

    // D2: fused conv1 -> h1(LDS) -> conv2 -> dpo
    fused_conv_kernel<<<512, 256, 0, stream>>>(
        x, Wt1, Wt2, b1, g1, bb1, b2, g2, bb2, lw, lb, dpo);
}

// Round 14
// 67.653 us; speedup vs baseline: 2.8156x; 1.0362x over previous
//
#include <hip/hip_runtime.h>
#include <hip/hip_bf16.h>

typedef unsigned short u16;
typedef short s8v __attribute__((ext_vector_type(8)));
typedef float f4v __attribute__((ext_vector_type(4)));
typedef u16 u16x8 __attribute__((ext_vector_type(8)));

static __device__ __forceinline__ u16 f2bf(float v) {
    __hip_bfloat16 h = __float2bfloat16(v);
    return *(u16*)&h;
}

// ---------------------------------------------------------------------------
// Dispatch 1: gather + weight prep (R10-proven, no cross-block deps).
//  b in [0,1024):    gather role (block re-scans its batch's target).
//  b in [1024,2176): Wt1 transpose.  b in [2176,2944): Wt2 transpose.
// Wt[f][kc*DIN + d] = bf16(w[f][d][kc]);  w is [256][DIN][3]
// ---------------------------------------------------------------------------
__global__ __launch_bounds__(256) void gather_prep_kernel(
    const float* __restrict__ x,
    const int*   __restrict__ target,
    const float* __restrict__ w1,
    const float* __restrict__ w2,
    u16* __restrict__ Wt1,
    u16* __restrict__ Wt2,
    float* __restrict__ out0)
{
    __shared__ int c[512];
    __shared__ int ridx[64];
    const int b = blockIdx.x, tid = threadIdx.x;

    if (b >= 1024) {
        if (b < 2176) {
            const int K = 1152, DIN = 384;
            int e = (b - 1024) * 256 + tid;
            int f = e / K;
            int rem = e - f * K;
            int kc = rem / DIN;
            int d = rem - kc * DIN;
            Wt1[e] = f2bf(w1[f * K + d * 3 + kc]);
        } else {
            const int K = 768, DIN = 256;
            int e = (b - 2176) * 256 + tid;
            int f = e / K;
            int rem = e - f * K;
            int kc = rem / DIN;
            int d = rem - kc * DIN;
            Wt2[e] = f2bf(w2[f * K + d * 3 + kc]);
        }
        return;
    }

    // ---- gather role ----
    const int n = b >> 5, sub = b & 31;
    c[tid]       = target[n * 512 + tid];
    c[tid + 256] = target[n * 512 + 256 + tid];
    __syncthreads();
    for (int off = 1; off < 512; off <<= 1) {
        int v0 = (tid       >= off) ? c[tid       - off] : 0;
        int v1 = (tid + 256 >= off) ? c[tid + 256 - off] : 0;
        __syncthreads();
        c[tid]       += v0;
        c[tid + 256] += v1;
        __syncthreads();
    }
    const int total = c[511];
    if (tid < 64) {
        int t = sub * 64 + tid;
        int lo = 0, hi = 512;
        while (lo < hi) {
            int mid = (lo + hi) >> 1;
            if (c[mid] <= t) lo = mid + 1; else hi = mid;
        }
        ridx[tid] = (t < total) ? min(lo, 511) : -1;
    }
    __syncthreads();

    const size_t xbase = (size_t)(n << 9) * 384;
    const size_t obase = ((size_t)(n << 11) + sub * 64) * 384;
    #pragma unroll 4
    for (int it = 0; it < 12; ++it) {
        int u  = tid + it * 256;
        int j  = u % 48;
        int rl = u / 48;
        int ie = ridx[rl];
        f4v v0 = {0.f, 0.f, 0.f, 0.f}, v1 = v0;
        if (ie >= 0) {
            const float* src = &x[xbase + (size_t)ie * 384];
            v0 = *(const f4v*)&src[j * 4];
            v1 = *(const f4v*)&src[(j + 48) * 4];
        }
        float* dst = &out0[obase + (size_t)rl * 384];
        __builtin_nontemporal_store(v0, (f4v*)&dst[j * 4]);
        __builtin_nontemporal_store(v1, (f4v*)&dst[(j + 48) * 4]);
    }
}

// ---------------------------------------------------------------------------
// Dispatch 2: FUSED conv1 -> LN1/ReLU -> h1(LDS) -> conv2 -> LN2/ReLU -> dot
// R14 change: A window staged ONCE into xw LDS (50 rows x 384 d bf16,
// slot-XOR swizzled) -> P1 K-steps read A-frags directly from xw (no per-step
// A staging).  Both phases are the same 2-barrier single-buffered-B loop.
// LDS map (73216 B -> 2 blocks/CU):
//  [0, 38400)      xw (P1) | h1 34x512B (P2, aliases dead xw)
//  [38400, 71168)  Bs 32 KB single buffer (both phases)
//  [71168, 73216)  redS[192] | redQ[192] | redP[128]
// Per block: 512 blocks XCD-swizzled, 256 thr = 4 waves, wave tile = cols
// 64wc..+63 of all rows; P1 3 m-frags (48-row window), P2 2 m-frags.
// ---------------------------------------------------------------------------
__global__ __launch_bounds__(256, 2) void fused_conv_kernel(
    const float* __restrict__ x,
    const u16* __restrict__ Wt1,   // [256][1152]
    const u16* __restrict__ Wt2,   // [256][768]
    const float* __restrict__ cb1, const float* __restrict__ g1,
    const float* __restrict__ bb1,
    const float* __restrict__ cb2, const float* __restrict__ g2,
    const float* __restrict__ bb2,
    const float* __restrict__ lw, const float* __restrict__ lbp,
    float* __restrict__ dpo)
{
    __shared__ __align__(128) char LDS[73216];
    char* Bs    = LDS + 38400;
    float* redS = (float*)(LDS + 71168);   // [48*4]
    float* redQ = (float*)(LDS + 71936);   // [48*4]
    float* redP = (float*)(LDS + 72704);   // [32*4]

    const int tid  = threadIdx.x;
    const int lane = tid & 63, wc = tid >> 6;
    const int lr = lane & 15, q4 = lane >> 4;
    const int sb = (blockIdx.x & 7) * 64 + (blockIdx.x >> 3);
    const int m0 = sb * 32;
    const int n  = m0 >> 9, l0 = m0 & 511;

    // B staging map: dest linear tid*16, source slot pre-swizzled (rule 21)
    const int b_r    = tid >> 3;
    const int b_slot = (tid & 7) ^ (b_r & 7);
    int boff[4];
    #pragma unroll
    for (int ni = 0; ni < 4; ni++) boff[ni] = (64 * wc + 16 * ni + lr) * 128;
    const int slot0 = ((q4)     ^ (lr & 7)) << 4;
    const int slot1 = ((q4 | 4) ^ (lr & 7)) << 4;

    // ---- prologue: stage xw = bf16(x[l0-9 .. l0+41)) once, swizzled ----
    // xw[j][slot s] at byte j*768 + ((s&~7)|((s&7)^(j&7)))*16, j in [0,50)
    for (int u = tid; u < 2400; u += 256) {          // 50 rows x 48 slots
        int j = u / 48, s = u - j * 48;
        int lp = l0 - 9 + j;
        f4v v0 = {0.f, 0.f, 0.f, 0.f}, v1 = v0;
        if (lp >= 0 && lp < 512) {
            const float* src = x + ((size_t)((n << 9) + lp)) * 384 + s * 8;
            v0 = *(const f4v*)src;
            v1 = *(const f4v*)(src + 4);
        }
        u16x8 r;
        #pragma unroll
        for (int jj = 0; jj < 4; jj++) { r[jj] = f2bf(v0[jj]); r[4 + jj] = f2bf(v1[jj]); }
        int ss = (s & ~7) | ((s & 7) ^ (j & 7));
        *(u16x8*)(LDS + j * 768 + ss * 16) = r;
    }

    auto xwread = [&](int j, int s) -> s8v {
        int ss = (s & ~7) | ((s & 7) ^ (j & 7));
        return *(const s8v*)(LDS + j * 768 + (ss << 4));
    };

    // ================= P1: conv1 over 48-row window, 18 K-steps ===========
    f4v acc[3][4];
    #pragma unroll
    for (int mi = 0; mi < 3; mi++)
        #pragma unroll
        for (int ni = 0; ni < 4; ni++) acc[mi][ni] = {0.f, 0.f, 0.f, 0.f};

    for (int t = 0; t < 18; ++t) {
        __syncthreads();   // t=0: xw ready; else: prev Bs reads done
        const int k0 = t * 64;
        const u16* bsrc = Wt1 + (size_t)b_r * 1152 + k0 + b_slot * 8;
        #pragma unroll
        for (int q = 0; q < 8; q++) {
            __builtin_amdgcn_global_load_lds(
                (const __attribute__((address_space(1))) void*)(bsrc + (size_t)q * 32 * 1152),
                (__attribute__((address_space(3))) void*)(Bs + q * 4096 + tid * 16),
                16, 0, 0);
        }
        __syncthreads();   // compiler drains vmcnt before barrier

        const int kc = k0 / 384;
        const int s0 = (k0 - kc * 384) >> 3;
        #pragma unroll
        for (int kk = 0; kk < 2; kk++) {
            const int sl = kk ? slot1 : slot0;
            const int s  = s0 + 4 * kk + q4;
            s8v a0 = xwread(lr + kc,      s);
            s8v a1 = xwread(16 + lr + kc, s);
            s8v a2 = xwread(32 + lr + kc, s);
            s8v b0 = *(const s8v*)(Bs + boff[0] + sl);
            s8v b1 = *(const s8v*)(Bs + boff[1] + sl);
            s8v b2 = *(const s8v*)(Bs + boff[2] + sl);
            s8v b3 = *(const s8v*)(Bs + boff[3] + sl);
            acc[0][0] = __builtin_amdgcn_mfma_f32_16x16x32_bf16(a0, b0, acc[0][0], 0, 0, 0);
            acc[0][1] = __builtin_amdgcn_mfma_f32_16x16x32_bf16(a0, b1, acc[0][1], 0, 0, 0);
            acc[0][2] = __builtin_amdgcn_mfma_f32_16x16x32_bf16(a0, b2, acc[0][2], 0, 0, 0);
            acc[0][3] = __builtin_amdgcn_mfma_f32_16x16x32_bf16(a0, b3, acc[0][3], 0, 0, 0);
            acc[1][0] = __builtin_amdgcn_mfma_f32_16x16x32_bf16(a1, b0, acc[1][0], 0, 0, 0);
            acc[1][1] = __builtin_amdgcn_mfma_f32_16x16x32_bf16(a1, b1, acc[1][1], 0, 0, 0);
            acc[1][2] = __builtin_amdgcn_mfma_f32_16x16x32_bf16(a1, b2, acc[1][2], 0, 0, 0);
            acc[1][3] = __builtin_amdgcn_mfma_f32_16x16x32_bf16(a1, b3, acc[1][3], 0, 0, 0);
            acc[2][0] = __builtin_amdgcn_mfma_f32_16x16x32_bf16(a2, b0, acc[2][0], 0, 0, 0);
            acc[2][1] = __builtin_amdgcn_mfma_f32_16x16x32_bf16(a2, b1, acc[2][1], 0, 0, 0);
            acc[2][2] = __builtin_amdgcn_mfma_f32_16x16x32_bf16(a2, b2, acc[2][2], 0, 0, 0);
            acc[2][3] = __builtin_amdgcn_mfma_f32_16x16x32_bf16(a2, b3, acc[2][3], 0, 0, 0);
        }
    }

    // ---- P1 epilogue: bias + LN1 + ReLU -> h1 LDS (34 rows, over xw) ----
    int col[4];
    float cbv[4], gv[4], bbv[4];
    #pragma unroll
    for (int ni = 0; ni < 4; ni++) {
        col[ni] = 64 * wc + 16 * ni + lr;
        cbv[ni] = cb1[col[ni]]; gv[ni] = g1[col[ni]]; bbv[ni] = bb1[col[ni]];
    }

    #pragma unroll
    for (int mi = 0; mi < 3; mi++)
        #pragma unroll
        for (int reg = 0; reg < 4; reg++) {
            float s = 0.f, q = 0.f;
            #pragma unroll
            for (int ni = 0; ni < 4; ni++) {
                float v = acc[mi][ni][reg] + cbv[ni];
                s += v; q += v * v;
            }
            #pragma unroll
            for (int msk = 1; msk < 16; msk <<= 1) {
                s += __shfl_xor(s, msk);
                q += __shfl_xor(q, msk);
            }
            if (lr == 0) {
                int rl = 16 * mi + 4 * q4 + reg;
                redS[rl * 4 + wc] = s;
                redQ[rl * 4 + wc] = q;
            }
        }
    __syncthreads();   // redS ready AND all xw reads done (h1 overwrites xw)

    #pragma unroll
    for (int mi = 0; mi < 3; mi++)
        #pragma unroll
        for (int reg = 0; reg < 4; reg++) {
            int rl = 16 * mi + 4 * q4 + reg;
            int h  = rl - 7;
            if (h >= 0 && h < 34) {
                float4 ps = *(float4*)&redS[rl * 4];
                float4 pq = *(float4*)&redQ[rl * 4];
                float mean = (ps.x + ps.y + ps.z + ps.w) * (1.f / 256.f);
                float var  = (pq.x + pq.y + pq.z + pq.w) * (1.f / 256.f) - mean * mean;
                float rs   = rsqrtf(var + 1e-5f);
                int l = l0 - 8 + rl;
                bool lv = (l >= 0 && l < 512);
                #pragma unroll
                for (int ni = 0; ni < 4; ni++) {
                    float v = acc[mi][ni][reg] + cbv[ni];
                    float o = lv ? fmaxf(0.f, (v - mean) * rs * gv[ni] + bbv[ni]) : 0.f;
                    int slot = (col[ni] >> 3) ^ (h & 7);
                    *(u16*)(LDS + h * 512 + slot * 16 + (col[ni] & 7) * 2) = f2bf(o);
                }
            }
        }

    // ================= P2: conv2 (A from h1 LDS), 12 K-steps ==============
    f4v acc2[2][4];
    #pragma unroll
    for (int mi = 0; mi < 2; mi++)
        #pragma unroll
        for (int ni = 0; ni < 4; ni++) acc2[mi][ni] = {0.f, 0.f, 0.f, 0.f};

    for (int t2 = 0; t2 < 12; ++t2) {
        __syncthreads();   // t2=0: h1 visible; else: prev Bs reads done
        const int k0 = t2 * 64;
        const u16* bsrc = Wt2 + (size_t)b_r * 768 + k0 + b_slot * 8;
        #pragma unroll
        for (int q = 0; q < 8; q++) {
            __builtin_amdgcn_global_load_lds(
                (const __attribute__((address_space(1))) void*)(bsrc + (size_t)q * 32 * 768),
                (__attribute__((address_space(3))) void*)(Bs + q * 4096 + tid * 16),
                16, 0, 0);
        }
        __syncthreads();   // compiler drains vmcnt before barrier

        const int kc2   = t2 >> 2;
        const int sbase = 8 * (t2 & 3);
        #pragma unroll
        for (int kk = 0; kk < 2; kk++) {
            const int sl = kk ? slot1 : slot0;
            s8v b0 = *(const s8v*)(Bs + boff[0] + sl);
            s8v b1 = *(const s8v*)(Bs + boff[1] + sl);
            s8v b2 = *(const s8v*)(Bs + boff[2] + sl);
            s8v b3 = *(const s8v*)(Bs + boff[3] + sl);
            s8v a0, a1;
            {
                int h = lr + kc2;
                int s = sbase + 4 * kk + q4;
                a0 = *(const s8v*)(LDS + h * 512 + ((s ^ (h & 7)) << 4));
                h = 16 + lr + kc2;
                a1 = *(const s8v*)(LDS + h * 512 + ((s ^ (h & 7)) << 4));
            }
            acc2[0][0] = __builtin_amdgcn_mfma_f32_16x16x32_bf16(a0, b0, acc2[0][0], 0, 0, 0);
            acc2[0][1] = __builtin_amdgcn_mfma_f32_16x16x32_bf16(a0, b1, acc2[0][1], 0, 0, 0);
            acc2[0][2] = __builtin_amdgcn_mfma_f32_16x16x32_bf16(a0, b2, acc2[0][2], 0, 0, 0);
            acc2[0][3] = __builtin_amdgcn_mfma_f32_16x16x32_bf16(a0, b3, acc2[0][3], 0, 0, 0);
            acc2[1][0] = __builtin_amdgcn_mfma_f32_16x16x32_bf16(a1, b0, acc2[1][0], 0, 0, 0);
            acc2[1][1] = __builtin_amdgcn_mfma_f32_16x16x32_bf16(a1, b1, acc2[1][1], 0, 0, 0);
            acc2[1][2] = __builtin_amdgcn_mfma_f32_16x16x32_bf16(a1, b2, acc2[1][2], 0, 0, 0);
            acc2[1][3] = __builtin_amdgcn_mfma_f32_16x16x32_bf16(a1, b3, acc2[1][3], 0, 0, 0);
        }
    }

    // ---- P2 epilogue: bias + LN2 + ReLU + dot(lin_w) -> dpo ----
    float cbv2[4], gv2[4], bbv2[4], lwv[4];
    #pragma unroll
    for (int ni = 0; ni < 4; ni++) {
        cbv2[ni] = cb2[col[ni]]; gv2[ni] = g2[col[ni]]; bbv2[ni] = bb2[col[ni]];
        lwv[ni]  = lw[col[ni]];
    }

    float sv[2][4], sq[2][4];
    #pragma unroll
    for (int mi = 0; mi < 2; mi++)
        #pragma unroll
        for (int reg = 0; reg < 4; reg++) {
            float s = 0.f, q = 0.f;
            #pragma unroll
            for (int ni = 0; ni < 4; ni++) {
                float v = acc2[mi][ni][reg] + cbv2[ni];
                s += v; q += v * v;
            }
            #pragma unroll
            for (int msk = 1; msk < 16; msk <<= 1) {
                s += __shfl_xor(s, msk);
                q += __shfl_xor(q, msk);
            }
            sv[mi][reg] = s; sq[mi][reg] = q;
        }
    __syncthreads();            // Bs/h1 reads done; reuse redS/redQ
    if (lr == 0) {
        #pragma unroll
        for (int mi = 0; mi < 2; mi++)
            #pragma unroll
            for (int reg = 0; reg < 4; reg++) {
                int rl = 16 * mi + 4 * q4 + reg;
                redS[rl * 4 + wc] = sv[mi][reg];
                redQ[rl * 4 + wc] = sq[mi][reg];
            }
    }
    __syncthreads();

    float pp[2][4];
    #pragma unroll
    for (int mi = 0; mi < 2; mi++)
        #pragma unroll
        for (int reg = 0; reg < 4; reg++) {
            int rl = 16 * mi + 4 * q4 + reg;
            float4 ps = *(float4*)&redS[rl * 4];
            float4 pq = *(float4*)&redQ[rl * 4];
            float mean = (ps.x + ps.y + ps.z + ps.w) * (1.f / 256.f);
            float var  = (pq.x + pq.y + pq.z + pq.w) * (1.f / 256.f) - mean * mean;
            float rs   = rsqrtf(var + 1e-5f);
            float p = 0.f;
            #pragma unroll
            for (int ni = 0; ni < 4; ni++) {
                float v = acc2[mi][ni][reg] + cbv2[ni];
                float o = fmaxf(0.f, (v - mean) * rs * gv2[ni] + bbv2[ni]);
                p += o * lwv[ni];
            }
            #pragma unroll
            for (int msk = 1; msk < 16; msk <<= 1) p += __shfl_xor(p, msk);
            pp[mi][reg] = p;
        }
    if (lr == 0) {
        #pragma unroll
        for (int mi = 0; mi < 2; mi++)
            #pragma unroll
            for (int reg = 0; reg < 4; reg++) {
                int rl = 16 * mi + 4 * q4 + reg;
                redP[rl * 4 + wc] = pp[mi][reg];
            }
    }
    __syncthreads();
    if (tid < 32) {
        float4 p4 = *(float4*)&redP[tid * 4];
        dpo[m0 + tid] = p4.x + p4.y + p4.z + p4.w + lbp[0];
    }
}

// ---------------------------------------------------------------------------
extern "C" void kernel_launch(void* const* d_in, const int* in_sizes, int n_in,
                              void* d_out, int out_size, void* d_ws, size_t ws_size,
                              hipStream_t stream) {
    const float* x   = (const float*)d_in[0];
    const float* w1  = (const float*)d_in[1];
    const float* b1  = (const float*)d_in[2];
    const float* g1  = (const float*)d_in[3];
    const float* bb1 = (const float*)d_in[4];
    const float* w2  = (const float*)d_in[5];
    const float* b2  = (const float*)d_in[6];
    const float* g2  = (const float*)d_in[7];
    const float* bb2 = (const float*)d_in[8];
    const float* lw  = (const float*)d_in[9];
    const float* lb  = (const float*)d_in[10];
    const int* target = (const int*)d_in[11];

    // ws layout (bytes): Wt1 589824 | Wt2 393216
    char* wsb = (char*)d_ws;
    u16*  Wt1 = (u16*)wsb;
    u16*  Wt2 = (u16*)(wsb + 589824);

    float* out0 = (float*)d_out;                  // [32, 2048, 384]
    float* dpo  = out0 + (size_t)32 * 2048 * 384; // [32, 512]

    // D1: gather (1024 blocks, self-contained scan) + weight prep
    gather_prep_kernel<<<2944, 256, 0, stream>>>(
        x, target, w1, w2, Wt1, Wt2, out0);

    // D2: fused conv1 -> h1(LDS) -> conv2 -> dpo (xw-resident A)
    fused_conv_kernel<<<512, 256, 0, stream>>>(
        x, Wt1, Wt2, b1, g1, bb1, b2, g2, bb2, lw, lb, dpo);
}